// Round 1
// baseline (416.207 us; speedup 1.0000x reference)
//
#include <hip/hip_runtime.h>
#include <cstdint>
#include <cstddef>

typedef float v4f __attribute__((ext_vector_type(4)));
typedef short short8 __attribute__((ext_vector_type(8)));

constexpr int B_ = 8, P_ = 16384, Q_ = 256, E_ = 128;

// ---------- helpers ----------
__device__ __forceinline__ unsigned int f2bf(float f) {
  unsigned int x = __float_as_uint(f);
  x += 0x7FFFu + ((x >> 16) & 1u);           // round-to-nearest-even
  return x >> 16;
}
__device__ __forceinline__ float softplus_f(float x) {
  return fmaxf(x, 0.f) + __logf(1.f + __expf(-fabsf(x)));
}
__device__ __forceinline__ short8 mk8(unsigned a, unsigned b, unsigned c, unsigned d) {
  union { unsigned u[4]; short8 s; } x;
  x.u[0] = a; x.u[1] = b; x.u[2] = c; x.u[3] = d; return x.s;
}
__device__ __forceinline__ float wsum(float v) {
#pragma unroll
  for (int o = 32; o; o >>= 1) v += __shfl_xor(v, o, 64);
  return v;
}

// Raw workgroup barrier that does NOT drain vmcnt: the global prefetch loads
// target registers only (no cross-wave visibility needed), so the barriers
// only have to order LDS traffic. __syncthreads() would emit
// s_waitcnt vmcnt(0) lgkmcnt(0) and kill the prefetch pipeline (the measured
// ~28% memory duty cycle). lgkmcnt(0) + s_barrier keeps loads in flight
// across the whole iteration (T3/T4 counted-wait pattern).
__device__ __forceinline__ void lds_barrier() {
  asm volatile("s_waitcnt lgkmcnt(0)" ::: "memory");
  __builtin_amdgcn_s_barrier();
}

// ---------- fused: prep + both GEMMs, split-K via fp32 atomics ----------
// grid = 8b x 32ks = 256 blocks x 512 threads. Block computes the FULL 256q x 128e
// tile for its 512-p K-chunk (16 steps of 32p). Per step, wave w owns p-rows
// 4w..4w+3 entirely (all 256 q), so softmax row sums are wave-local (butterfly).
// LDS tiles, col-major pair-packed (word = bf16{p even, p odd}):
//   A1t[16][260], EZt[16][260] (q fast, pitch 260), SBt[16][132], STt[16][132].
// Writes: linear b128 (conflict-free). Frag reads: 4x ds_read_b32 stride 260/132
// -> 2 lanes/bank (free). MFMA 16x16x32: k=32 = the whole step.
// NOTE: unified regfile usage is ~256/wave (128 VGPR + 128 AGPR acc) -> hard
// cap of 8 waves/CU; occupancy cannot be raised, so latency hiding must come
// from keeping vmcnt in flight across barriers (lds_barrier above).
__global__ __launch_bounds__(512, 2) void fused_all(
    const float* __restrict__ mlv, const int* __restrict__ mask,
    const float* __restrict__ seg, float* __restrict__ part,
    float* __restrict__ negsum, float* __restrict__ ppsum,
    float* __restrict__ segsum, float* __restrict__ nnzb)
{
  __shared__ __align__(16) unsigned int lds[12544];   // 50176 B
  unsigned int* A1t = lds;            // 4160 words
  unsigned int* EZt = lds + 4160;     // 4160
  unsigned int* SBt = lds + 8320;     // 2112
  unsigned int* STt = lds + 10432;    // 2112

  const int t = threadIdx.x, w = t >> 6, l = t & 63;
  const int lm = l & 15, quad = l >> 4;
  const int wr = w & 3, wc = w >> 2;
  const int jj = l >> 5, le = l & 31;
  const int b = blockIdx.x >> 5, ks = blockIdx.x & 31;

  v4f acc0[4][4], acc1[4][4];
#pragma unroll
  for (int i = 0; i < 4; ++i)
#pragma unroll
    for (int j = 0; j < 4; ++j) { acc0[i][j] = (v4f)0.f; acc1[i][j] = (v4f)0.f; }
  float accN[4] = {0.f,0.f,0.f,0.f};
  float accP[4] = {0.f,0.f,0.f,0.f};
  float accS[4] = {0.f,0.f,0.f,0.f};
  float cnt = 0.f;

  const float* mp = mlv + ((size_t)b * P_ + ks * 512 + 4 * w) * Q_ + 4 * l;
  const int*   kp = mask + ((size_t)b * P_ + ks * 512 + 4 * w) * Q_ + 4 * l;
  const float* sp = seg + ((size_t)b * P_ + ks * 512 + 4 * w + 2 * jj) * E_ + 4 * le;

  float4 X[4]; int4 M[4]; float4 S0, S1;
#pragma unroll
  for (int r = 0; r < 4; ++r) {
    X[r] = *(const float4*)(mp + (size_t)r * Q_);
    M[r] = *(const int4*)(kp + (size_t)r * Q_);
  }
  S0 = *(const float4*)(sp);
  S1 = *(const float4*)(sp + E_);

  for (int it = 0; it < 16; ++it) {
    // ---- unpack & compute ----
    float xs[4][4]; int ms[4][4];
#pragma unroll
    for (int r = 0; r < 4; ++r) {
      xs[r][0] = X[r].x; xs[r][1] = X[r].y; xs[r][2] = X[r].z; xs[r][3] = X[r].w;
      ms[r][0] = M[r].x; ms[r][1] = M[r].y; ms[r][2] = M[r].z; ms[r][3] = M[r].w;
    }
    float sv0[4] = {S0.x, S0.y, S0.z, S0.w};
    float sv1[4] = {S1.x, S1.y, S1.z, S1.w};

    // ---- prefetch next step (stays in flight across BOTH barriers now) ----
    if (it < 15) {
      mp += 32 * Q_; kp += 32 * Q_; sp += 32 * E_;
#pragma unroll
      for (int r = 0; r < 4; ++r) {
        X[r] = *(const float4*)(mp + (size_t)r * Q_);
        M[r] = *(const int4*)(kp + (size_t)r * Q_);
      }
      S0 = *(const float4*)(sp);
      S1 = *(const float4*)(sp + E_);
    }

    float ez[4][4], rs[4];
#pragma unroll
    for (int r = 0; r < 4; ++r) {
      float s = 0.f;
#pragma unroll
      for (int j = 0; j < 4; ++j) {
        const bool mm = ms[r][j] != 0;
        const float e = mm ? __expf(xs[r][j]) : 0.f;
        ez[r][j] = e; s += e;
        accN[j] += __logf(1.f + e);                    // softplus(x) on masked
      }
      rs[r] = s;
    }
#pragma unroll
    for (int r = 0; r < 4; ++r) rs[r] = wsum(rs[r]);
    float inv[4];
#pragma unroll
    for (int r = 0; r < 4; ++r) inv[r] = (rs[r] > 0.f) ? (1.f / rs[r]) : 0.f;

    unsigned int a1p[2][4], ezp[2][4];
#pragma unroll
    for (int jp = 0; jp < 2; ++jp)
#pragma unroll
      for (int j = 0; j < 4; ++j) {
        const int r0 = 2 * jp, r1 = 2 * jp + 1;
        a1p[jp][j] = f2bf(ms[r0][j] ? -xs[r0][j] : 0.f)
                   | (f2bf(ms[r1][j] ? -xs[r1][j] : 0.f) << 16);
        const float p0 = ez[r0][j] * inv[r0];
        const float p1 = ez[r1][j] * inv[r1];
        accP[j] += p0 + p1;
        ezp[jp][j] = f2bf(p0) | (f2bf(p1) << 16);
      }
    unsigned int sb[4], st_[4];
#pragma unroll
    for (int j = 0; j < 4; ++j) {
      accS[j] += sv0[j] + sv1[j];
      cnt += ((sv0[j] > 0.f) ? 1.f : 0.f) + ((sv1[j] > 0.f) ? 1.f : 0.f);
      sb[j]  = ((sv0[j] > 0.f) ? 0x3F80u : 0u) | ((sv1[j] > 0.f) ? 0x3F800000u : 0u);
      st_[j] = f2bf(sv0[j]) | (f2bf(sv1[j]) << 16);
    }

    // previous MFMA phase done reading LDS (own ds_reads already consumed;
    // barrier orders across waves). vmcnt deliberately NOT drained.
    lds_barrier();
    { uint4 v; v.x=a1p[0][0]; v.y=a1p[0][1]; v.z=a1p[0][2]; v.w=a1p[0][3];
      *(uint4*)(A1t + (2*w)     * 260 + 4*l) = v; }
    { uint4 v; v.x=a1p[1][0]; v.y=a1p[1][1]; v.z=a1p[1][2]; v.w=a1p[1][3];
      *(uint4*)(A1t + (2*w + 1) * 260 + 4*l) = v; }
    { uint4 v; v.x=ezp[0][0]; v.y=ezp[0][1]; v.z=ezp[0][2]; v.w=ezp[0][3];
      *(uint4*)(EZt + (2*w)     * 260 + 4*l) = v; }
    { uint4 v; v.x=ezp[1][0]; v.y=ezp[1][1]; v.z=ezp[1][2]; v.w=ezp[1][3];
      *(uint4*)(EZt + (2*w + 1) * 260 + 4*l) = v; }
    { uint4 v; v.x=sb[0]; v.y=sb[1]; v.z=sb[2]; v.w=sb[3];
      *(uint4*)(SBt + (2*w + jj) * 132 + 4*le) = v; }
    { uint4 v; v.x=st_[0]; v.y=st_[1]; v.z=st_[2]; v.w=st_[3];
      *(uint4*)(STt + (2*w + jj) * 132 + 4*le) = v; }
    // own ds_writes flushed (lgkmcnt(0)) + barrier -> visible to all waves.
    lds_barrier();

    // ---- MFMA phase: k=32 (whole step) ----
    short8 af0[4], af1[4], bf0[4], bf1[4];
#pragma unroll
    for (int i = 0; i < 4; ++i) {
      const int q_abs = wr * 64 + i * 16 + lm;
      const int c0 = 4 * quad;
      af0[i] = mk8(A1t[c0*260 + q_abs], A1t[(c0+1)*260 + q_abs],
                   A1t[(c0+2)*260 + q_abs], A1t[(c0+3)*260 + q_abs]);
      af1[i] = mk8(EZt[c0*260 + q_abs], EZt[(c0+1)*260 + q_abs],
                   EZt[(c0+2)*260 + q_abs], EZt[(c0+3)*260 + q_abs]);
    }
#pragma unroll
    for (int j = 0; j < 4; ++j) {
      const int e_abs = wc * 64 + j * 16 + lm;
      const int c0 = 4 * quad;
      bf0[j] = mk8(SBt[c0*132 + e_abs], SBt[(c0+1)*132 + e_abs],
                   SBt[(c0+2)*132 + e_abs], SBt[(c0+3)*132 + e_abs]);
      bf1[j] = mk8(STt[c0*132 + e_abs], STt[(c0+1)*132 + e_abs],
                   STt[(c0+2)*132 + e_abs], STt[(c0+3)*132 + e_abs]);
    }
#pragma unroll
    for (int i = 0; i < 4; ++i)
#pragma unroll
      for (int j = 0; j < 4; ++j) {
        acc0[i][j] = __builtin_amdgcn_mfma_f32_16x16x32_bf16(af0[i], bf0[j], acc0[i][j], 0, 0, 0);
        acc1[i][j] = __builtin_amdgcn_mfma_f32_16x16x32_bf16(af1[i], bf1[j], acc1[i][j], 0, 0, 0);
      }
  }

  // ---- reductions ----
  __syncthreads();   // full drain fine here: no loads in flight after last iter
  float* fr = (float*)lds;
#pragma unroll
  for (int j = 0; j < 4; ++j) {
    fr[w * 256 + 4 * l + j] = accN[j];
    fr[2048 + w * 256 + 4 * l + j] = accP[j];
    fr[4096 + (2 * w + jj) * 128 + 4 * le + j] = accS[j];
  }
  __syncthreads();
  if (t < 256) {
    float sn = 0.f, sq = 0.f;
#pragma unroll
    for (int k = 0; k < 8; ++k) { sn += fr[k * 256 + t]; sq += fr[2048 + k * 256 + t]; }
    atomicAdd(&negsum[b * 256 + t], sn);
    atomicAdd(&ppsum[b * 256 + t], sq);
  } else if (t < 384) {
    const int e = t - 256;
    float ss = 0.f;
#pragma unroll
    for (int k = 0; k < 16; ++k) ss += fr[4096 + k * 128 + e];
    atomicAdd(&segsum[b * 128 + e], ss);
  }
  cnt = wsum(cnt);
  if (l == 0) atomicAdd(&nnzb[b], cnt);

  // ---- split-K accumulate ----
  float* p0 = part + (size_t)b * 32768;
  float* p1 = part + (size_t)(8 + b) * 32768;
#pragma unroll
  for (int i = 0; i < 4; ++i)
#pragma unroll
    for (int r = 0; r < 4; ++r) {
      const int q = wr * 64 + i * 16 + quad * 4 + r;
#pragma unroll
      for (int j = 0; j < 4; ++j) {
        const int e = wc * 64 + j * 16 + lm;
        atomicAdd(&p0[q * 128 + e], acc0[i][j][r]);
        atomicAdd(&p1[q * 128 + e], acc1[i][j][r]);
      }
    }
}

// ---------- epilogue: all closed-form cost terms ----------
__global__ __launch_bounds__(128) void epilogue(
    const float* __restrict__ part,
    const float* __restrict__ negsum, const float* __restrict__ ppsum,
    const float* __restrict__ segsum, const float* __restrict__ nnzb,
    const float* __restrict__ logits, const float* __restrict__ ppos,
    const float* __restrict__ chol, const float* __restrict__ tpos,
    const float* __restrict__ imgsz, float* __restrict__ out)
{
  const int bq = blockIdx.x;          // b*256 + q
  const int b = bq >> 8;
  const int e = threadIdx.x;
  const int qe = (bq & 255) * 128 + e;
  const float g1 = part[(size_t)b * 32768 + qe];
  const float g2 = part[(size_t)(8 + b) * 32768 + qe];

  const float nnz = fmaxf(nnzb[b], 1.f);
  const float mask_cost = (negsum[bq] + g1) / nnz;
  const float dice = 1.f - (2.f * g2 + 1.f) / (ppsum[bq] + segsum[b * 128 + e] + 1.f);
  const float cls = softplus_f(-logits[bq]);
  const float px = ppos[bq * 2], py = ppos[bq * 2 + 1];
  const float tx = tpos[(b * 128 + e) * 2], ty = tpos[(b * 128 + e) * 2 + 1];
  const float dx = px - tx, dy = py - ty;
  const float ax = fabsf(dx), ay = fabsf(dy);
  const float hx = (ax < 1.f) ? 0.5f * dx * dx : ax - 0.5f;
  const float hy = (ay < 1.f) ? 0.5f * dy * dy : ay - 0.5f;
  const float huber = 0.5f * (hx + hy);
  const float sx = imgsz[b * 2], sy = imgsz[b * 2 + 1];
  const float L00 = chol[bq * 4 + 0], L10 = chol[bq * 4 + 2], L11 = chol[bq * 4 + 3];
  const float d0 = (tx - px) * sx, d1 = (ty - py) * sy;
  const float z0 = d0 / L00;
  const float z1 = (d1 - L10 * z0) / L11;
  const float nll = 0.5f * (z0 * z0 + z1 * z1) + 1.8378770664093453f + __logf(L00) + __logf(L11);
  const float lik = 1.f - __expf(-nll);
  out[bq * 128 + e] = 2.f * cls + 5.f * mask_cost + 5.f * dice + huber + 0.5f * nll + 0.5f * lik;
}

// ---------- launcher ----------
extern "C" void kernel_launch(void* const* d_in, const int* in_sizes, int n_in,
                              void* d_out, int out_size, void* d_ws, size_t ws_size,
                              hipStream_t stream)
{
  (void)in_sizes; (void)n_in; (void)out_size; (void)ws_size;
  const float* logits = (const float*)d_in[0];
  const float* mlv    = (const float*)d_in[1];
  const int*   mask   = (const int*)d_in[2];
  const float* seg    = (const float*)d_in[3];
  const float* ppos   = (const float*)d_in[4];
  const float* chol   = (const float*)d_in[5];
  const float* tpos   = (const float*)d_in[6];
  const float* imgsz  = (const float*)d_in[7];

  char* ws = (char*)d_ws;
  float* part   = (float*)(ws);                    // 2097152 B  [2][8][256][128]
  float* negsum = (float*)(ws + 2097152);          // 8192 B
  float* ppsum  = (float*)(ws + 2105344);          // 8192 B
  float* segsum = (float*)(ws + 2113536);          // 4096 B
  float* nnzb   = (float*)(ws + 2117632);          // 32 B

  hipMemsetAsync(ws, 0, 2117664, stream);
  fused_all<<<256, 512, 0, stream>>>(mlv, mask, seg, part, negsum, ppsum, segsum, nnzb);
  epilogue<<<2048, 128, 0, stream>>>(part, negsum, ppsum, segsum, nnzb,
                                     logits, ppos, chol, tpos, imgsz, (float*)d_out);
}